// Round 7
// baseline (228.072 us; speedup 1.0000x reference)
//
#include <hip/hip_runtime.h>
#include <hip/hip_cooperative_groups.h>

// H2GCNConv: out[:, 0:128]   = segment_sum(w1 * x[col1], row1)
//            out[:, 128:256] = segment_sum(w2 * x[col2], row2)
// N = 50000, d = 128, out stride = 256 floats.
//
// Round 13: falsifier from r12 fired -- two totally different scatter
// implementations (LDS-atomic r4, ballot r6) give IDENTICAL totals (212.1 vs
// 212.9) with accum fixed at ~96us. The ~116us residual is therefore not
// binning compute; first-principles puts prep at ~15-20us. Suspect: fixed
// multi-dispatch overhead (launch/gap/ramp between graph nodes). Test+fix in
// one move: fuse cvt+scatter+accum into ONE cooperative kernel (512 WG x
// 1024 thr = exactly 2 WG/CU x 256 CU co-resident; 49.5 KB LDS pool union)
// with a single grid.sync() between producer phases and accum. Accum logic
// is the proven r4/r6 algorithm verbatim (1024 thr: rows/wave 8->4). Record
// split rec(u32)+rl(u8) cuts inter traffic 19->12 MB each way.
// Either outcome is informative: overhead theory right -> ~120-135us;
// wrong -> ~210us but all inside one dispatch = full counter visibility.

#define N_NODES 50000
#define D 128
#define OUT_STRIDE 256

#define BSHIFT 6
#define BROWS 64
#define NBUCK ((N_NODES + BROWS - 1) >> BSHIFT)   // 782
#define BBITS 10                       // 782 < 1024
#define CHUNK 5120                     // edges per scatter task
#define NTHR 1024                      // 16 waves
#define NWAVE 16
#define WSEG (CHUNK / NWAVE)           // 320 records per wave
#define SITERS (WSEG / 64)             // 5 iterations per wave
#define ACAP 4096                      // per-bucket record cap (g2 mean 2046)
#define GRID 512                       // 2 WG/CU x 256 CU co-resident

// ---- LDS pool byte offsets ----
#define SM_SIZE 50688
// scatter view
#define SO_REC  0                      // u32[5120]              20480
#define SO_RL   20480                  // u8[5120]                5120
#define SO_HWC  25600                  // u16[16][782]           25024
#define SO_WSUM 50624                  // int[16]                   64
// accum view
#define AO_RECS 0                      // u32[4096]              16384
#define AO_OUTB 16384                  // u32[4096]              16384
#define AO_RL   32768                  // u8[4096]                4096
#define AO_CROW 36864                  // int[64]
#define AO_CUR  37120                  // int[64]
#define AO_RST  37376                  // int[64]
#define AO_TOT  37632                  // int

typedef float vf2 __attribute__((ext_vector_type(2)));

static inline size_t align256(size_t x) { return (x + 255) & ~(size_t)255; }

__device__ __forceinline__ unsigned f32_to_bf16_bits(float f) {
    unsigned u = __float_as_uint(f);
    return (u + 0x7fffu + ((u >> 16) & 1u)) >> 16;   // RNE
}

// match-any over BITS-bit value v across the wave (valid lanes only).
template<int BITS>
__device__ __forceinline__ unsigned long long wave_match(int v, bool valid) {
    unsigned long long m = __ballot(valid ? 1 : 0);
    #pragma unroll
    for (int k = 0; k < BITS; ++k) {
        unsigned long long vb = __ballot((v >> k) & 1);
        m &= ((v >> k) & 1) ? vb : ~vb;
    }
    return m;
}

// ---------------- phase 0: x -> bf16x2 pack (grid-stride) -------------------

__device__ __forceinline__ void dev_cvt(const float* __restrict__ x,
                                        unsigned* __restrict__ xb, int n4) {
    for (long long i = (long long)blockIdx.x * NTHR + threadIdx.x; i < n4;
         i += (long long)gridDim.x * NTHR) {
        float4 v = ((const float4*)x)[i];
        unsigned a = f32_to_bf16_bits(v.x);
        unsigned b = f32_to_bf16_bits(v.y);
        unsigned c = f32_to_bf16_bits(v.z);
        unsigned d = f32_to_bf16_bits(v.w);
        ((uint2*)xb)[i] = make_uint2(a | (b << 16), c | (d << 16));
    }
}

// ---------------- phase 1: chunk -> bin-sorted contiguous block -------------
// Ballot-match once, cache (bin|rowlocal|pos)+rec in registers; wave-private
// u16 hists; no atomics. Writes inter_rec/inter_rl contiguously + ends.

__device__ void dev_scatter(int cid,
        const int* __restrict__ ei1, const float* __restrict__ w1, int E1, int nch1,
        const int* __restrict__ ei2, const float* __restrict__ w2, int E2,
        unsigned* __restrict__ irec, unsigned char* __restrict__ irl,
        int* __restrict__ ends, char* sm) {
    unsigned*       stage_rec = (unsigned*)(sm + SO_REC);
    unsigned char*  stage_rl  = (unsigned char*)(sm + SO_RL);
    unsigned short* hwc       = (unsigned short*)(sm + SO_HWC);   // [16][NBUCK]
    int*            wsum      = (int*)(sm + SO_WSUM);

    int g = (cid < nch1) ? 0 : 1;
    int chunk = g ? cid - nch1 : cid;
    const int*   ei = g ? ei2 : ei1;
    const float* w  = g ? w2  : w1;
    int E           = g ? E2  : E1;
    int e0  = chunk * CHUNK;
    int cnt = min(CHUNK, E - e0);

    int t = threadIdx.x, lane = t & 63, wid = t >> 6;
    unsigned long long below = (1ull << lane) - 1ull;
    for (int i = t; i < (NWAVE * NBUCK) / 2; i += NTHR) ((int*)hwc)[i] = 0;
    __syncthreads();

    int s0 = wid * WSEG, s1 = min(cnt, s0 + WSEG);
    unsigned meta[SITERS];     // bin(10) | rowlocal(6)<<10 | pos(16)<<16
    unsigned recs[SITERS];     // col | bf16(w)<<16
    #pragma unroll
    for (int k = 0; k < SITERS; ++k) {
        int i = s0 + k * 64 + lane;
        bool v = (i < s1);
        int row = v ? ei[e0 + i] : 0;
        int col = v ? ei[E + e0 + i] : 0;
        float wv = v ? w[e0 + i] : 0.f;
        int bb = row >> BSHIFT;
        unsigned long long m = wave_match<BBITS>(bb, v);
        unsigned rank = (unsigned)__popcll(m & below);
        unsigned base = hwc[wid * NBUCK + bb];
        if (v && (m & below) == 0)
            hwc[wid * NBUCK + bb] = (unsigned short)(base + (unsigned)__popcll(m));
        meta[k] = (unsigned)bb | ((unsigned)(row & 63) << 10) | ((base + rank) << 16);
        recs[k] = (unsigned)col | (f32_to_bf16_bits(wv) << 16);
    }
    __syncthreads();
    // scan: thread t owns bin t; two passes over hwc (no big reg array)
    {
        int tot = 0;
        if (t < NBUCK) {
            #pragma unroll
            for (int q = 0; q < NWAVE; ++q) tot += hwc[q * NBUCK + t];
        }
        int s = tot;
        #pragma unroll
        for (int d2 = 1; d2 < 64; d2 <<= 1) { int u = __shfl_up(s, d2, 64); if (lane >= d2) s += u; }
        if (lane == 63) wsum[wid] = s;
        __syncthreads();
        int add = 0;
        #pragma unroll
        for (int k = 0; k < NWAVE; ++k) if (k < wid) add += wsum[k];
        s += add;
        if (t < NBUCK) {
            int a = s - tot;
            #pragma unroll
            for (int q = 0; q < NWAVE; ++q) {
                int hq = hwc[q * NBUCK + t];
                hwc[q * NBUCK + t] = (unsigned short)a;
                a += hq;
            }
            ends[(size_t)cid * NBUCK + t] = a;     // inclusive chunk-local end
        }
    }
    __syncthreads();
    // pass 2: place cached records
    #pragma unroll
    for (int k = 0; k < SITERS; ++k) {
        int i = s0 + k * 64 + lane;
        if (i < s1) {
            unsigned mk = meta[k];
            unsigned bb = mk & 1023u;
            unsigned pos = (mk >> 16) + hwc[wid * NBUCK + bb];
            stage_rec[pos] = recs[k];
            stage_rl[pos] = (unsigned char)((mk >> 10) & 63u);
        }
    }
    __syncthreads();
    // flush coalesced
    for (int i = t; i < cnt; i += NTHR) {
        irec[(size_t)cid * CHUNK + i] = stage_rec[i];
        irl[(size_t)cid * CHUNK + i]  = stage_rl[i];
    }
}

// ---------------- phase 2: bucket accum (r4/r6 algorithm, 1024 thr) ---------

__device__ __forceinline__ void fma_rec(unsigned p, unsigned rec, float& ax, float& ay) {
    float w = __int_as_float((int)(rec & 0xffff0000u));   // bf16 bits high
    ax += w * __int_as_float((int)(p << 16));
    ay += w * __int_as_float((int)(p & 0xffff0000u));
}

__device__ void dev_accum(int b, int g, int nch1, int nch2,
        const unsigned* __restrict__ irec, const unsigned char* __restrict__ irl,
        const int* __restrict__ ends, const unsigned* __restrict__ xb,
        float* __restrict__ out, char* sm) {
    unsigned*      arecs = (unsigned*)(sm + AO_RECS);
    unsigned*      aoutb = (unsigned*)(sm + AO_OUTB);
    unsigned char* arl   = (unsigned char*)(sm + AO_RL);
    int* crow   = (int*)(sm + AO_CROW);
    int* cur    = (int*)(sm + AO_CUR);
    int* rstart = (int*)(sm + AO_RST);
    int* total  = (int*)(sm + AO_TOT);

    int c0 = g ? nch1 : 0;
    int nc = g ? nch2 : nch1;
    int t = threadIdx.x, lane = t & 63, wid = t >> 6;
    if (t < BROWS) crow[t] = 0;
    if (t == 0) *total = 0;
    __syncthreads();
    // phase A: pull this bucket's segment from each chunk
    for (int ci = t; ci < nc; ci += NTHR) {
        const int* ep = ends + (size_t)(c0 + ci) * NBUCK;
        int s = b ? ep[b - 1] : 0;
        int e = ep[b];
        int n = e - s;
        if (!n) continue;
        int dst = atomicAdd(total, n);
        const unsigned* sr = irec + (size_t)(c0 + ci) * CHUNK + s;
        const unsigned char* sl = irl + (size_t)(c0 + ci) * CHUNK + s;
        int k = 0;
        for (; k + 2 <= n; k += 2) {
            unsigned r0 = sr[k], r1 = sr[k + 1];
            unsigned char l0 = sl[k], l1 = sl[k + 1];
            int p0 = dst + k, p1 = dst + k + 1;
            if (p0 < ACAP) { arl[p0] = l0; arecs[p0] = r0; atomicAdd(&crow[l0], 1); }
            if (p1 < ACAP) { arl[p1] = l1; arecs[p1] = r1; atomicAdd(&crow[l1], 1); }
        }
        if (k < n) {
            unsigned r0 = sr[k];
            unsigned char l0 = sl[k];
            int p0 = dst + k;
            if (p0 < ACAP) { arl[p0] = l0; arecs[p0] = r0; atomicAdd(&crow[l0], 1); }
        }
    }
    __syncthreads();
    int cnt = min(*total, ACAP);
    if (wid == 0) {                      // exclusive scan of 64 row counts
        int v = crow[lane], s = v;
        #pragma unroll
        for (int d2 = 1; d2 < 64; d2 <<= 1) { int u = __shfl_up(s, d2, 64); if (lane >= d2) s += u; }
        cur[lane] = s - v;
        rstart[lane] = s - v;
    }
    __syncthreads();
    for (int i = t; i < cnt; i += NTHR) {   // rank-scatter by row
        int pos = atomicAdd(&cur[arl[i]], 1);
        aoutb[pos] = arecs[i];
    }
    __syncthreads();                        // cur[r] = end of row r
    // each wave register-accumulates 4 rows
    for (int r = wid * 4; r < wid * 4 + 4; ++r) {
        int grow = (b << BSHIFT) + r;
        if (grow >= N_NODES) break;
        int rs = rstart[r], re = cur[r];
        float ax = 0.f, ay = 0.f;
        int j = rs;
        for (; j + 4 <= re; j += 4) {
            unsigned c0r = aoutb[j];
            unsigned c1r = aoutb[j + 1];
            unsigned c2r = aoutb[j + 2];
            unsigned c3r = aoutb[j + 3];
            unsigned p0 = xb[(size_t)(c0r & 0xffffu) * 64 + lane];
            unsigned p1 = xb[(size_t)(c1r & 0xffffu) * 64 + lane];
            unsigned p2 = xb[(size_t)(c2r & 0xffffu) * 64 + lane];
            unsigned p3 = xb[(size_t)(c3r & 0xffffu) * 64 + lane];
            fma_rec(p0, c0r, ax, ay);
            fma_rec(p1, c1r, ax, ay);
            fma_rec(p2, c2r, ax, ay);
            fma_rec(p3, c3r, ax, ay);
        }
        for (; j < re; ++j) {
            unsigned cr = aoutb[j];
            unsigned p = xb[(size_t)(cr & 0xffffu) * 64 + lane];
            fma_rec(p, cr, ax, ay);
        }
        vf2 rv; rv.x = ax; rv.y = ay;
        vf2* o = (vf2*)(out + (size_t)grow * OUT_STRIDE + g * D);
        __builtin_nontemporal_store(rv, o + lane);
    }
}

// ---------------- fused cooperative kernel ----------------------------------

__global__ void __launch_bounds__(NTHR, 8) k_fused(
        const int* ei1, const float* w1, int E1, int nch1,
        const int* ei2, const float* w2, int E2, int nch2, int ncht,
        unsigned* irec, unsigned char* irl, int* ends,
        const float* x, unsigned* xb, int n4, float* out) {
    __shared__ alignas(16) char sm[SM_SIZE];
    dev_cvt(x, xb, n4);
    if ((int)blockIdx.x < ncht)
        dev_scatter(blockIdx.x, ei1, w1, E1, nch1, ei2, w2, E2, irec, irl, ends, sm);
    cooperative_groups::this_grid().sync();
    for (int task = blockIdx.x; task < 2 * NBUCK; task += gridDim.x) {
        int g = task >= NBUCK;
        int b = g ? task - NBUCK : task;
        __syncthreads();
        dev_accum(b, g, nch1, nch2, irec, irl, ends, xb, out, sm);
    }
}

// ---------------- fallback pair (same device code, 2 dispatches) ------------

__global__ void __launch_bounds__(NTHR, 8) k_prep(
        const int* ei1, const float* w1, int E1, int nch1,
        const int* ei2, const float* w2, int E2, int ncht,
        unsigned* irec, unsigned char* irl, int* ends,
        const float* x, unsigned* xb, int n4) {
    __shared__ alignas(16) char sm[SM_SIZE];
    dev_cvt(x, xb, n4);
    if ((int)blockIdx.x < ncht)
        dev_scatter(blockIdx.x, ei1, w1, E1, nch1, ei2, w2, E2, irec, irl, ends, sm);
}

__global__ void __launch_bounds__(NTHR, 8) k_accum(
        const unsigned* irec, const unsigned char* irl, const int* ends,
        const unsigned* xb, float* out, int nch1, int nch2) {
    __shared__ alignas(16) char sm[AO_TOT + 16];
    int task = blockIdx.x;
    int g = task >= NBUCK;
    int b = g ? task - NBUCK : task;
    dev_accum(b, g, nch1, nch2, irec, irl, ends, xb, out, sm);
}

// ---------------- atomic scatter (fallback if ws too small) ----------------

__global__ void spmm_scatter(const float* __restrict__ x,
                             const int* __restrict__ ei,
                             const float* __restrict__ w,
                             float* __restrict__ out,
                             int E, int col_off) {
    long long gid = (long long)blockIdx.x * blockDim.x + threadIdx.x;
    int e    = (int)(gid >> 5);
    int lane = (int)(gid & 31);
    if (e >= E) return;
    int row  = ei[e];
    int col  = ei[E + e];
    float wv = w[e];
    const float4* xv = (const float4*)(x + (size_t)col * D);
    float4 v = xv[lane];
    float* o = out + (size_t)row * OUT_STRIDE + col_off + lane * 4;
    atomicAdd(o + 0, wv * v.x);
    atomicAdd(o + 1, wv * v.y);
    atomicAdd(o + 2, wv * v.z);
    atomicAdd(o + 3, wv * v.w);
}

extern "C" void kernel_launch(void* const* d_in, const int* in_sizes, int n_in,
                              void* d_out, int out_size, void* d_ws, size_t ws_size,
                              hipStream_t stream) {
    const int*   ei1_p = (const int*)d_in[1];
    const float* w1_p  = (const float*)d_in[2];
    const int*   ei2_p = (const int*)d_in[3];
    const float* w2_p  = (const float*)d_in[4];
    const float* x_p   = (const float*)d_in[0];
    float* out_p = (float*)d_out;

    int E1 = in_sizes[1] / 2;   // 800000
    int E2 = in_sizes[3] / 2;   // 1600000
    const int block = 256;

    int nch1 = (E1 + CHUNK - 1) / CHUNK;   // 157
    int nch2 = (E2 + CHUNK - 1) / CHUNK;   // 313
    int ncht = nch1 + nch2;                // 470
    int n4   = N_NODES * 32;

    // Workspace: inter_rec | inter_rl | ends | xb
    size_t rec_b  = align256((size_t)ncht * CHUNK * sizeof(unsigned));
    size_t rl_b   = align256((size_t)ncht * CHUNK);
    size_t ends_b = align256((size_t)ncht * NBUCK * sizeof(int));
    size_t xb_b   = align256((size_t)N_NODES * 64 * sizeof(unsigned));
    size_t o_rec  = 0;
    size_t o_rl   = o_rec + rec_b;
    size_t o_ends = o_rl + rl_b;
    size_t o_xb   = o_ends + ends_b;
    size_t needed = o_xb + xb_b;

    bool shape_ok = (ncht <= GRID) && (nch1 <= NTHR) && (nch2 <= NTHR);

    if (ws_size < needed || !shape_ok) {
        (void)hipMemsetAsync(d_out, 0, (size_t)out_size * sizeof(float), stream);
        long long th1 = (long long)E1 * 32;
        spmm_scatter<<<(int)((th1 + block - 1) / block), block, 0, stream>>>(
            x_p, ei1_p, w1_p, out_p, E1, 0);
        long long th2 = (long long)E2 * 32;
        spmm_scatter<<<(int)((th2 + block - 1) / block), block, 0, stream>>>(
            x_p, ei2_p, w2_p, out_p, E2, D);
        return;
    }

    char* ws = (char*)d_ws;
    unsigned*      irec = (unsigned*)(ws + o_rec);
    unsigned char* irl  = (unsigned char*)(ws + o_rl);
    int*           ends = (int*)(ws + o_ends);
    unsigned*      xb   = (unsigned*)(ws + o_xb);

    // cooperative path: guaranteed co-residency check first (host-side only)
    int occ = 0;
    hipError_t qe = hipOccupancyMaxActiveBlocksPerMultiprocessor(&occ, k_fused, NTHR, 0);
    if (qe == hipSuccess && occ >= 2) {
        void* ka[] = { (void*)&ei1_p, (void*)&w1_p, (void*)&E1, (void*)&nch1,
                       (void*)&ei2_p, (void*)&w2_p, (void*)&E2, (void*)&nch2,
                       (void*)&ncht, (void*)&irec, (void*)&irl, (void*)&ends,
                       (void*)&x_p, (void*)&xb, (void*)&n4, (void*)&out_p };
        (void)hipLaunchCooperativeKernel((const void*)k_fused, dim3(GRID), dim3(NTHR),
                                         ka, 0, stream);
        return;
    }

    // fallback: same code as two dispatches
    k_prep<<<GRID, NTHR, 0, stream>>>(ei1_p, w1_p, E1, nch1, ei2_p, w2_p, E2,
                                      ncht, irec, irl, ends, x_p, xb, n4);
    k_accum<<<2 * NBUCK, NTHR, 0, stream>>>(irec, irl, ends, xb, out_p, nch1, nch2);
}

// Round 8
// 223.835 us; speedup vs baseline: 1.0189x; 1.0189x over previous
//
#include <hip/hip_runtime.h>

// H2GCNConv: out[:, 0:128]   = segment_sum(w1 * x[col1], row1)
//            out[:, 128:256] = segment_sum(w2 * x[col2], row2)
// N = 50000, d = 128, out stride = 256 floats.
//
// Round 14 accounting (r13 fused single-dispatch = 205us, r6 split accum =
// 96us, overhead ~23us): prep has been ~90us of REAL GPU time all along,
// hidden below accum's 96 in top-5. Theory: prep runs at 2 WG/CU (50-77KB
// LDS) with ~300-400cy dependent chains per iteration (load -> 10-ballot
// match -> dependent LDS hwc RMW) -- 16 waves/CU can't hide it. Fix: shrink
// prep LDS to 33KB (stage u32+u8 split, CHUNK 4096, 8-wave u16 hists) -> 4
// WG/CU / 32 waves, SITERS 8, cvt folded in as grid-stride prologue (no cvt
// block tail). Accum: back to the PROVEN split-dispatch form (512 thr, 1564
// HW-scheduled blocks -- fused static assignment cost ~40us in r13) with
// r13's rec/rl split arrays.
// Pipeline: k_prep (cvt + scatter) -> k_accum.

#define N_NODES 50000
#define D 128
#define OUT_STRIDE 256

#define BSHIFT 6
#define BROWS 64
#define NBUCK ((N_NODES + BROWS - 1) >> BSHIFT)   // 782
#define BBITS 10                       // 782 < 1024
#define CHUNK 4096                     // edges per scatter WG
#define NTHR 512                       // 8 waves
#define NWAVE 8
#define WSEG (CHUNK / NWAVE)           // 512 records per wave
#define SITERS (WSEG / 64)             // 8 iterations per wave
#define ACAP 3072                      // per-bucket record cap (g2 mean 2046, +22 sigma)

typedef float vf2 __attribute__((ext_vector_type(2)));

static inline size_t align256(size_t x) { return (x + 255) & ~(size_t)255; }

__device__ __forceinline__ unsigned f32_to_bf16_bits(float f) {
    unsigned u = __float_as_uint(f);
    return (u + 0x7fffu + ((u >> 16) & 1u)) >> 16;   // RNE
}

// match-any over BITS-bit value v across the wave (valid lanes only).
template<int BITS>
__device__ __forceinline__ unsigned long long wave_match(int v, bool valid) {
    unsigned long long m = __ballot(valid ? 1 : 0);
    #pragma unroll
    for (int k = 0; k < BITS; ++k) {
        unsigned long long vb = __ballot((v >> k) & 1);
        m &= ((v >> k) & 1) ? vb : ~vb;
    }
    return m;
}

// ---------------- 1. prep: cvt prologue + chunk bin-sort -------------------
// 33 KB LDS -> 4 WG/CU (32 waves) for latency hiding. Ballot-match once,
// cache (bin|rowlocal|pos)+rec in 16 VGPRs; wave-private u16 hists; zero
// atomics. Coalesced contiguous flush + chunk-major ends.

__global__ void __launch_bounds__(NTHR) k_prep(
        const int* __restrict__ ei1, const float* __restrict__ w1, int E1, int nch1,
        const int* __restrict__ ei2, const float* __restrict__ w2, int E2, int ncht,
        unsigned* __restrict__ irec, unsigned char* __restrict__ irl,
        int* __restrict__ ends,
        const float* __restrict__ x, unsigned* __restrict__ xb, int n4) {
    __shared__ unsigned stage_rec[CHUNK];           // 16 KB
    __shared__ unsigned char stage_rl[CHUNK];       // 4 KB
    __shared__ unsigned short hwc[NWAVE][NBUCK];    // 12.5 KB
    __shared__ int wsum[NWAVE];

    int t = threadIdx.x, lane = t & 63, wid = t >> 6;

    // ---- cvt prologue: x -> bf16x2, grid-strided over all prep blocks ----
    for (long long i = (long long)blockIdx.x * NTHR + t; i < n4;
         i += (long long)gridDim.x * NTHR) {
        float4 v = ((const float4*)x)[i];
        unsigned a = f32_to_bf16_bits(v.x);
        unsigned b = f32_to_bf16_bits(v.y);
        unsigned c = f32_to_bf16_bits(v.z);
        unsigned d = f32_to_bf16_bits(v.w);
        ((uint2*)xb)[i] = make_uint2(a | (b << 16), c | (d << 16));
    }

    // ---- scatter ----
    int cid = blockIdx.x;
    if (cid >= ncht) return;
    int g = (cid < nch1) ? 0 : 1;
    int chunk = g ? cid - nch1 : cid;
    const int*   ei = g ? ei2 : ei1;
    const float* w  = g ? w2  : w1;
    int E           = g ? E2  : E1;
    int e0  = chunk * CHUNK;
    int cnt = min(CHUNK, E - e0);

    unsigned long long below = (1ull << lane) - 1ull;
    for (int i = t; i < (NWAVE * NBUCK) / 2; i += NTHR) ((int*)hwc)[i] = 0;
    __syncthreads();

    int s0 = wid * WSEG, s1 = min(cnt, s0 + WSEG);
    unsigned meta[SITERS];     // bin(10) | rowlocal(6)<<10 | pos(16)<<16
    unsigned recs[SITERS];     // col | bf16(w)<<16
    // pass 1: load + ballot-match + wave-private hist (plain LDS RMW)
    #pragma unroll
    for (int k = 0; k < SITERS; ++k) {
        int i = s0 + k * 64 + lane;
        bool v = (i < s1);
        int row = v ? ei[e0 + i] : 0;
        int col = v ? ei[E + e0 + i] : 0;
        float wv = v ? w[e0 + i] : 0.f;
        int bb = row >> BSHIFT;
        unsigned long long m = wave_match<BBITS>(bb, v);
        unsigned rank = (unsigned)__popcll(m & below);
        unsigned base = hwc[wid][bb];
        if (v && (m & below) == 0)                 // leader of its bin-group
            hwc[wid][bb] = (unsigned short)(base + (unsigned)__popcll(m));
        meta[k] = (unsigned)bb | ((unsigned)(row & 63) << 10) | ((base + rank) << 16);
        recs[k] = (unsigned)col | (f32_to_bf16_bits(wv) << 16);
    }
    __syncthreads();
    // scan: bins 2t, 2t+1; per-wave prefix laid back into hwc; write ends
    {
        int b0 = 2 * t, b1 = b0 + 1;
        int h0[NWAVE], h1[NWAVE];
        int t0 = 0, t1 = 0;
        if (b0 < NBUCK) {
            #pragma unroll
            for (int q = 0; q < NWAVE; ++q) { h0[q] = hwc[q][b0]; t0 += h0[q]; }
        }
        if (b1 < NBUCK) {
            #pragma unroll
            for (int q = 0; q < NWAVE; ++q) { h1[q] = hwc[q][b1]; t1 += h1[q]; }
        }
        int p = t0 + t1, s = p;
        #pragma unroll
        for (int d2 = 1; d2 < 64; d2 <<= 1) { int u = __shfl_up(s, d2, 64); if (lane >= d2) s += u; }
        if (lane == 63) wsum[wid] = s;
        __syncthreads();
        int add = 0;
        #pragma unroll
        for (int k = 0; k < NWAVE; ++k) if (k < wid) add += wsum[k];
        s += add;
        int excl = s - p;
        if (b0 < NBUCK) {
            int a = excl;
            #pragma unroll
            for (int q = 0; q < NWAVE; ++q) { int h = h0[q]; hwc[q][b0] = (unsigned short)a; a += h; }
            ends[(size_t)cid * NBUCK + b0] = a;    // inclusive chunk-local end
        }
        if (b1 < NBUCK) {
            int a = excl + t0;
            #pragma unroll
            for (int q = 0; q < NWAVE; ++q) { int h = h1[q]; hwc[q][b1] = (unsigned short)a; a += h; }
            ends[(size_t)cid * NBUCK + b1] = a;
        }
    }
    __syncthreads();
    // pass 2: place cached records
    #pragma unroll
    for (int k = 0; k < SITERS; ++k) {
        int i = s0 + k * 64 + lane;
        if (i < s1) {
            unsigned mk = meta[k];
            unsigned bb = mk & 1023u;
            unsigned pos = (mk >> 16) + hwc[wid][bb];
            stage_rec[pos] = recs[k];
            stage_rl[pos] = (unsigned char)((mk >> 10) & 63u);
        }
    }
    __syncthreads();
    // flush coalesced
    for (int i = t; i < cnt; i += NTHR) {
        irec[(size_t)cid * CHUNK + i] = stage_rec[i];
        irl[(size_t)cid * CHUNK + i]  = stage_rl[i];
    }
}

// ---------------- 2. bucket accum (proven r6 form, 512 thr, HW-balanced) ---

__device__ __forceinline__ void fma_rec(unsigned p, unsigned rec, float& ax, float& ay) {
    float w = __int_as_float((int)(rec & 0xffff0000u));   // bf16 bits high
    ax += w * __int_as_float((int)(p << 16));
    ay += w * __int_as_float((int)(p & 0xffff0000u));
}

__global__ void __launch_bounds__(NTHR) k_accum(
        const unsigned* __restrict__ irec, const unsigned char* __restrict__ irl,
        const int* __restrict__ ends, const unsigned* __restrict__ xb,
        float* __restrict__ out, int nch1, int nch2) {
    int task = blockIdx.x;
    int g = task >= NBUCK;
    int b = g ? task - NBUCK : task;
    int c0 = g ? nch1 : 0;
    int nc = g ? nch2 : nch1;

    __shared__ unsigned arecs[ACAP];       // 12 KB
    __shared__ unsigned aoutb[ACAP];       // 12 KB
    __shared__ unsigned char arl[ACAP];    // 3 KB
    __shared__ int crow[BROWS], cur[BROWS], rstart[BROWS];
    __shared__ int total;
    int t = threadIdx.x, lane = t & 63, wid = t >> 6;
    if (t < BROWS) crow[t] = 0;
    if (t == 0) total = 0;
    __syncthreads();
    // phase A: pull this bucket's segment from each chunk
    for (int ci = t; ci < nc; ci += NTHR) {
        const int* ep = ends + (size_t)(c0 + ci) * NBUCK;
        int s = b ? ep[b - 1] : 0;
        int e = ep[b];
        int n = e - s;
        if (!n) continue;
        int dst = atomicAdd(&total, n);
        const unsigned* sr = irec + (size_t)(c0 + ci) * CHUNK + s;
        const unsigned char* sl = irl + (size_t)(c0 + ci) * CHUNK + s;
        int k = 0;
        for (; k + 2 <= n; k += 2) {
            unsigned r0 = sr[k], r1 = sr[k + 1];
            unsigned char l0 = sl[k], l1 = sl[k + 1];
            int p0 = dst + k, p1 = dst + k + 1;
            if (p0 < ACAP) { arl[p0] = l0; arecs[p0] = r0; atomicAdd(&crow[l0], 1); }
            if (p1 < ACAP) { arl[p1] = l1; arecs[p1] = r1; atomicAdd(&crow[l1], 1); }
        }
        if (k < n) {
            unsigned r0 = sr[k];
            unsigned char l0 = sl[k];
            int p0 = dst + k;
            if (p0 < ACAP) { arl[p0] = l0; arecs[p0] = r0; atomicAdd(&crow[l0], 1); }
        }
    }
    __syncthreads();
    int cnt = min(total, ACAP);
    if (wid == 0) {                      // exclusive scan of 64 row counts
        int v = crow[lane], s = v;
        #pragma unroll
        for (int d2 = 1; d2 < 64; d2 <<= 1) { int u = __shfl_up(s, d2, 64); if (lane >= d2) s += u; }
        cur[lane] = s - v;
        rstart[lane] = s - v;
    }
    __syncthreads();
    for (int i = t; i < cnt; i += NTHR) {   // rank-scatter by row
        int pos = atomicAdd(&cur[arl[i]], 1);
        aoutb[pos] = arecs[i];
    }
    __syncthreads();                        // cur[r] = end of row r
    // each wave register-accumulates 8 rows
    for (int r = wid * 8; r < wid * 8 + 8; ++r) {
        int grow = (b << BSHIFT) + r;
        if (grow >= N_NODES) break;
        int rs = rstart[r], re = cur[r];
        float ax = 0.f, ay = 0.f;
        int j = rs;
        for (; j + 4 <= re; j += 4) {
            unsigned c0r = aoutb[j];
            unsigned c1r = aoutb[j + 1];
            unsigned c2r = aoutb[j + 2];
            unsigned c3r = aoutb[j + 3];
            unsigned p0 = xb[(size_t)(c0r & 0xffffu) * 64 + lane];
            unsigned p1 = xb[(size_t)(c1r & 0xffffu) * 64 + lane];
            unsigned p2 = xb[(size_t)(c2r & 0xffffu) * 64 + lane];
            unsigned p3 = xb[(size_t)(c3r & 0xffffu) * 64 + lane];
            fma_rec(p0, c0r, ax, ay);
            fma_rec(p1, c1r, ax, ay);
            fma_rec(p2, c2r, ax, ay);
            fma_rec(p3, c3r, ax, ay);
        }
        for (; j < re; ++j) {
            unsigned cr = aoutb[j];
            unsigned p = xb[(size_t)(cr & 0xffffu) * 64 + lane];
            fma_rec(p, cr, ax, ay);
        }
        vf2 rv; rv.x = ax; rv.y = ay;
        vf2* o = (vf2*)(out + (size_t)grow * OUT_STRIDE + g * D);
        __builtin_nontemporal_store(rv, o + lane);
    }
}

// ---------------- atomic scatter (fallback if ws too small) ----------------

__global__ void spmm_scatter(const float* __restrict__ x,
                             const int* __restrict__ ei,
                             const float* __restrict__ w,
                             float* __restrict__ out,
                             int E, int col_off) {
    long long gid = (long long)blockIdx.x * blockDim.x + threadIdx.x;
    int e    = (int)(gid >> 5);
    int lane = (int)(gid & 31);
    if (e >= E) return;
    int row  = ei[e];
    int col  = ei[E + e];
    float wv = w[e];
    const float4* xv = (const float4*)(x + (size_t)col * D);
    float4 v = xv[lane];
    float* o = out + (size_t)row * OUT_STRIDE + col_off + lane * 4;
    atomicAdd(o + 0, wv * v.x);
    atomicAdd(o + 1, wv * v.y);
    atomicAdd(o + 2, wv * v.z);
    atomicAdd(o + 3, wv * v.w);
}

extern "C" void kernel_launch(void* const* d_in, const int* in_sizes, int n_in,
                              void* d_out, int out_size, void* d_ws, size_t ws_size,
                              hipStream_t stream) {
    const float* x_p   = (const float*)d_in[0];
    const int*   ei1_p = (const int*)d_in[1];
    const float* w1_p  = (const float*)d_in[2];
    const int*   ei2_p = (const int*)d_in[3];
    const float* w2_p  = (const float*)d_in[4];
    float* out_p = (float*)d_out;

    int E1 = in_sizes[1] / 2;   // 800000
    int E2 = in_sizes[3] / 2;   // 1600000
    const int block = 256;

    int nch1 = (E1 + CHUNK - 1) / CHUNK;   // 196
    int nch2 = (E2 + CHUNK - 1) / CHUNK;   // 391
    int ncht = nch1 + nch2;                // 587
    int n4   = N_NODES * 32;

    // Workspace: inter_rec | inter_rl | ends | xb
    size_t rec_b  = align256((size_t)ncht * CHUNK * sizeof(unsigned));
    size_t rl_b   = align256((size_t)ncht * CHUNK);
    size_t ends_b = align256((size_t)ncht * NBUCK * sizeof(int));
    size_t xb_b   = align256((size_t)N_NODES * 64 * sizeof(unsigned));
    size_t o_rec  = 0;
    size_t o_rl   = o_rec + rec_b;
    size_t o_ends = o_rl + rl_b;
    size_t o_xb   = o_ends + ends_b;
    size_t needed = o_xb + xb_b;

    if (ws_size < needed) {
        (void)hipMemsetAsync(d_out, 0, (size_t)out_size * sizeof(float), stream);
        long long th1 = (long long)E1 * 32;
        spmm_scatter<<<(int)((th1 + block - 1) / block), block, 0, stream>>>(
            x_p, ei1_p, w1_p, out_p, E1, 0);
        long long th2 = (long long)E2 * 32;
        spmm_scatter<<<(int)((th2 + block - 1) / block), block, 0, stream>>>(
            x_p, ei2_p, w2_p, out_p, E2, D);
        return;
    }

    char* ws = (char*)d_ws;
    unsigned*      irec = (unsigned*)(ws + o_rec);
    unsigned char* irl  = (unsigned char*)(ws + o_rl);
    int*           ends = (int*)(ws + o_ends);
    unsigned*      xb   = (unsigned*)(ws + o_xb);

    // 1. cvt + bin-sort (33 KB LDS -> 4 WG/CU)
    k_prep<<<ncht, NTHR, 0, stream>>>(ei1_p, w1_p, E1, nch1, ei2_p, w2_p, E2,
                                      ncht, irec, irl, ends, x_p, xb, n4);

    // 2. segment pull + in-LDS row sort + register accumulate (HW-balanced)
    k_accum<<<2 * NBUCK, NTHR, 0, stream>>>(irec, irl, ends, xb, out_p,
                                            nch1, nch2);
}